// Round 12
// baseline (211.219 us; speedup 1.0000x reference)
//
#include <hip/hip_runtime.h>
#include <hip/hip_bf16.h>

#define D 64
#define ED 32
#define NN 50000
#define EE 800000
#define NT64 (EE / 64)   // 12500 64-edge tiles, exact
#define NWN (NN / 16)    // 3125 16-node tiles, exact

#define PREP_N (4 * D * D + D * ED)          // 18432 prep elements
#define NB_PREP ((PREP_N + 255) / 256)       // 72
#define NB_ZERO ((NN / 4 + 255) / 256)       // 49  (NN % 4 == 0)
#define NB_NODE ((NWN + 3) / 4)              // 782
#define NB_HIST ((EE / 4 + 255) / 256)       // 782 (EE % 4 == 0)
#define NB_SCAN ((NN + 255) / 256)           // 196

typedef __attribute__((ext_vector_type(8))) short bf16x8;
typedef __attribute__((ext_vector_type(4))) float f32x4;
typedef __attribute__((ext_vector_type(4))) unsigned uint4v;
typedef __attribute__((ext_vector_type(4))) int int4v;

__device__ __forceinline__ short f2bf(float f) {
    __hip_bfloat16 h = __float2bfloat16(f);
    return *reinterpret_cast<short*>(&h);
}
__device__ __forceinline__ float bfhi2f(unsigned w) { return __uint_as_float(w & 0xFFFF0000u); }
__device__ __forceinline__ float bflo2f(unsigned w) { return __uint_as_float(w << 16); }
__device__ __forceinline__ unsigned packqv(float q, float v) {
    return (unsigned)(unsigned short)f2bf(q) | ((unsigned)(unsigned short)f2bf(v) << 16);
}

// Fused: weight prep + deg/gctr zeroing (round-9 proven, edge tables now
// COLUMN-PERMUTED: table row j holds original W column 4*(j&15)+(j>>4), so
// agg's C-fragment (lane lr, reg h) maps to logical dim 4*lr+h -> 16B gathers).
__global__ void prep_zero(const float* __restrict__ Wk, const float* __restrict__ Wq,
                          const float* __restrict__ Wv, const float* __restrict__ Ws,
                          unsigned short* __restrict__ WnT,
                          unsigned short* __restrict__ WgT, unsigned short* __restrict__ WvT,
                          int* __restrict__ deg, int* __restrict__ gctr) {
    const int b = blockIdx.x;
    if (b == 0 && threadIdx.x == 0) *gctr = 0;
    if (b < NB_PREP) {
        const int i = b * 256 + threadIdx.x;
        if (i < 4 * D * D) {
            // node tables stay in natural layout (node_hist epilogue uses 16h+lr)
            const int m = i >> 12, col = (i >> 6) & 63, k = i & 63;
            const float* W = (m == 0) ? Ws : (m == 1) ? Wk : (m == 2) ? Wq : Wv;
            WnT[i] = (unsigned short)f2bf(W[k * D + col]);
        } else {
            const int j = i - 4 * D * D;
            if (j < D * ED) {
                const int c = j >> 5, k = j & 31;
                const int cp = 4 * (c & 15) + (c >> 4);     // permuted column
                const size_t off = (size_t)(D + k) * D + cp;
                WgT[j] = (unsigned short)f2bf(Wk[off] + Wq[off]);
                WvT[j] = (unsigned short)f2bf(Wv[off]);
            }
        }
    } else {
        const int i = (b - NB_PREP) * 256 + threadIdx.x;   // int4 index
        if (i < NN / 4) ((int4v*)deg)[i] = (int4v){0, 0, 0, 0};
    }
}

// Mega-kernel: node MFMA transforms (pre-packed WnT) + dst histogram.
__global__ __launch_bounds__(256, 4)
void node_hist(const float* __restrict__ x, const unsigned short* __restrict__ WnT,
               const float* __restrict__ bk, const float* __restrict__ bq,
               const float* __restrict__ bv, const float* __restrict__ bias,
               float* __restrict__ kx, unsigned* __restrict__ qv, float* __restrict__ out,
               const int* __restrict__ dstI, int* __restrict__ deg) {
    const int b = blockIdx.x;
    if (b >= NB_NODE) {
        const int t = (b - NB_NODE) * 256 + threadIdx.x;
        const int e = 4 * t;
        if (e + 4 <= EE) {
            const int4v d4 = __builtin_nontemporal_load((const int4v*)(dstI + e));
#pragma unroll
            for (int r = 0; r < 4; ++r) atomicAdd(&deg[d4[r]], 1);
        }
        return;
    }
    const int lane = threadIdx.x & 63;
    const int wid  = b * 4 + (threadIdx.x >> 6);
    if (wid >= NWN) return;
    const int lg = lane >> 4, lr = lane & 15;
    const int n0 = wid * 16;

    const float* xp = x + (size_t)(n0 + lr) * D + 8 * lg;
    const f32x4 x00 = *(const f32x4*)xp;
    const f32x4 x01 = *(const f32x4*)(xp + 4);
    const f32x4 x10 = *(const f32x4*)(xp + 32);
    const f32x4 x11 = *(const f32x4*)(xp + 36);
    bf16x8 af0, af1;
#pragma unroll
    for (int e = 0; e < 4; ++e) {
        af0[e] = f2bf(x00[e]); af0[e + 4] = f2bf(x01[e]);
        af1[e] = f2bf(x10[e]); af1[e + 4] = f2bf(x11[e]);
    }

    f32x4 acc[4], accQ[4];
#pragma unroll
    for (int m = 0; m < 4; ++m) {
        f32x4* A = (m == 2) ? accQ : acc;
#pragma unroll
        for (int h = 0; h < 4; ++h) {
            const bf16x8 b0 = *(const bf16x8*)(WnT + (size_t)(m * D + 16 * h + lr) * D + 8 * lg);
            const bf16x8 b1 = *(const bf16x8*)(WnT + (size_t)(m * D + 16 * h + lr) * D + 32 + 8 * lg);
            A[h] = __builtin_amdgcn_mfma_f32_16x16x32_bf16(af0, b0, (f32x4)(0.f), 0, 0, 0);
            A[h] = __builtin_amdgcn_mfma_f32_16x16x32_bf16(af1, b1, A[h], 0, 0, 0);
        }
        if (m == 0) {
#pragma unroll
            for (int r = 0; r < 4; ++r)
#pragma unroll
                for (int h = 0; h < 4; ++h)
                    out[(size_t)(n0 + 4 * lg + r) * D + 16 * h + lr] = acc[h][r] + bias[16 * h + lr];
        } else if (m == 1) {
#pragma unroll
            for (int r = 0; r < 4; ++r)
#pragma unroll
                for (int h = 0; h < 4; ++h)
                    kx[(size_t)(n0 + 4 * lg + r) * D + 16 * h + lr] = acc[h][r] + bk[16 * h + lr];
        } else if (m == 3) {
#pragma unroll
            for (int r = 0; r < 4; ++r)
#pragma unroll
                for (int h = 0; h < 4; ++h)
                    qv[(size_t)(n0 + 4 * lg + r) * D + 16 * h + lr] =
                        packqv(accQ[h][r] + bq[16 * h + lr], acc[h][r] + bv[16 * h + lr]);
        }
    }
}

// Exclusive scan with atomic global base (round-11 proven).
__global__ void k_scanA(const int* __restrict__ deg, int* __restrict__ off,
                        int* __restrict__ gctr) {
    __shared__ int s_tmp[256];
    __shared__ int s_base;
    const int t = threadIdx.x, i = blockIdx.x * 256 + t;
    const int v = (i < NN) ? deg[i] : 0;
    s_tmp[t] = v;
    __syncthreads();
    for (int d = 1; d < 256; d <<= 1) {
        const int add = (t >= d) ? s_tmp[t - d] : 0;
        __syncthreads();
        s_tmp[t] += add;
        __syncthreads();
    }
    if (t == 255) s_base = atomicAdd(gctr, s_tmp[255]);
    __syncthreads();
    if (i < NN) off[i] = s_base + s_tmp[t] - v;
}

// Scatter, 4 edges/thread (round-11 proven).
__global__ void k_scatter4(const int* __restrict__ srcI, const int* __restrict__ dstI,
                           int* __restrict__ off, unsigned long long* __restrict__ rec) {
    const int t = blockIdx.x * 256 + threadIdx.x;
    const int e = 4 * t;
    if (e + 4 > EE) return;
    const int4v s4 = __builtin_nontemporal_load((const int4v*)(srcI + e));
    const int4v d4 = __builtin_nontemporal_load((const int4v*)(dstI + e));
#pragma unroll
    for (int r = 0; r < 4; ++r) {
        const int s = s4[r], d = d4[r];
        const int p = atomicAdd(&off[d], 1);
        rec[p] = ((unsigned long long)(unsigned)(e + r) << 32)
               | (unsigned)(s | (d << 16));
    }
}

// Edge-parallel aggregation over dst-grouped edges. Round-9 structure
// (launch_bounds(256,3), single-group batching) + permuted-column C layout:
// lane lr's 4 accumulator values are logical dims 4*lr..4*lr+3, so qv/kx
// gathers are ONE 16B load each per C-row (8 loads/group vs 32 scalars).
__global__ __launch_bounds__(256, 3)
void agg_sorted(const unsigned* __restrict__ rec, const float* __restrict__ ea,
                const unsigned short* __restrict__ WgT, const unsigned short* __restrict__ WvT,
                const float* __restrict__ kx, const unsigned* __restrict__ qv,
                float* __restrict__ out) {
    const int lane = threadIdx.x & 63;
    const int wid  = blockIdx.x * 4 + (threadIdx.x >> 6);   // tile id, grid exact
    const int lg = lane >> 4;
    const int lr = lane & 15;
    const int e0 = wid * 64;

    bf16x8 bg[4], bvf[4];
#pragma unroll
    for (int h = 0; h < 4; ++h) {
        bg[h]  = *(const bf16x8*)(WgT + (size_t)(16 * h + lr) * ED + 8 * lg);
        bvf[h] = *(const bf16x8*)(WvT + (size_t)(16 * h + lr) * ED + 8 * lg);
    }

#pragma unroll
    for (int g = 0; g < 4; ++g) {
        const int gb = e0 + 16 * g;
        const uint4v rA = *(const uint4v*)(rec + 2 * (gb + 4 * lg));
        const uint4v rB = *(const uint4v*)(rec + 2 * (gb + 4 * lg) + 4);
        int dR[4], sR[4];
        dR[0] = (int)(rA.x >> 16); sR[0] = (int)(rA.x & 0xFFFFu);
        dR[1] = (int)(rA.z >> 16); sR[1] = (int)(rA.z & 0xFFFFu);
        dR[2] = (int)(rB.x >> 16); sR[2] = (int)(rB.x & 0xFFFFu);
        dR[3] = (int)(rB.z >> 16); sR[3] = (int)(rB.z & 0xFFFFu);

        const unsigned pl = rec[2 * (gb + lr) + 1];
        const float* ap = ea + (size_t)pl * ED + 8 * lg;
        const f32x4 a0 = __builtin_nontemporal_load((const f32x4*)ap);
        const f32x4 a1 = __builtin_nontemporal_load((const f32x4*)(ap + 4));

        // vector gathers: per C-row one uint4 (qv) + one f32x4 (kx), dims 4lr..+3
        uint4v qd[4];
        f32x4  kd[4];
#pragma unroll
        for (int r = 0; r < 4; ++r) {
            qd[r] = *(const uint4v*)(qv + (size_t)sR[r] * D + 4 * lr);
            kd[r] = *(const f32x4*)(kx + (size_t)dR[r] * D + 4 * lr);
        }

        bf16x8 af;
#pragma unroll
        for (int e2 = 0; e2 < 4; ++e2) { af[e2] = f2bf(a0[e2]); af[e2 + 4] = f2bf(a1[e2]); }

        f32x4 accG[4], accV[4];
#pragma unroll
        for (int h = 0; h < 4; ++h) {
            accG[h] = __builtin_amdgcn_mfma_f32_16x16x32_bf16(af, bg[h],  (f32x4)(0.f), 0, 0, 0);
            accV[h] = __builtin_amdgcn_mfma_f32_16x16x32_bf16(af, bvf[h], (f32x4)(0.f), 0, 0, 0);
        }

        // msg[r][h]: edge gb+4lg+r, logical dim 4lr+h
        float msg[4][4];
#pragma unroll
        for (int r = 0; r < 4; ++r)
#pragma unroll
            for (int h = 0; h < 4; ++h) {
                const float z = accG[h][r] + kd[r][h] + bflo2f(qd[r][h]);
                const float v = accV[h][r] + bfhi2f(qd[r][h]);
                msg[r][h] = v * __builtin_amdgcn_rcpf(1.0f + __expf(-z));
            }

        bool done[4] = {false, false, false, false};
        while (true) {
            int m0 = 0x7FFFFFFF;
#pragma unroll
            for (int r = 0; r < 4; ++r) m0 = min(m0, done[r] ? 0x7FFFFFFF : dR[r]);
            m0 = min(m0, __shfl_xor(m0, 16, 64));
            m0 = min(m0, __shfl_xor(m0, 32, 64));
            if (m0 == 0x7FFFFFFF) break;          // wave-uniform exit
            float sh[4];
#pragma unroll
            for (int h = 0; h < 4; ++h) {
                float a = 0.f;
#pragma unroll
                for (int r = 0; r < 4; ++r) a += (dR[r] == m0) ? msg[r][h] : 0.f;
                a += __shfl_xor(a, 16, 64);
                a += __shfl_xor(a, 32, 64);
                sh[h] = a;
            }
#pragma unroll
            for (int r = 0; r < 4; ++r) done[r] = done[r] || (dR[r] == m0);
            if (lane < 16) {
                float* op = out + (size_t)m0 * D + 4 * lane;
#pragma unroll
                for (int h = 0; h < 4; ++h)
                    unsafeAtomicAdd(&op[h], sh[h]);
            }
        }
    }
}

extern "C" void kernel_launch(void* const* d_in, const int* in_sizes, int n_in,
                              void* d_out, int out_size, void* d_ws, size_t ws_size,
                              hipStream_t stream) {
    const float* x    = (const float*)d_in[0];
    const int*   eidx = (const int*)d_in[1];      // [2, E]: row0=src, row1=dst
    const float* eatt = (const float*)d_in[2];
    const float* Wk   = (const float*)d_in[3];
    const float* bk   = (const float*)d_in[4];
    const float* Wq   = (const float*)d_in[5];
    const float* bq   = (const float*)d_in[6];
    const float* Wv   = (const float*)d_in[7];
    const float* bv   = (const float*)d_in[8];
    const float* Ws   = (const float*)d_in[9];
    const float* bias = (const float*)d_in[10];
    float* out = (float*)d_out;

    // workspace carve (offsets keep 16B alignment)
    char* w = (char*)d_ws;
    float*    kx  = (float*)w;            w += (size_t)NN * D * 4;   // 12.8 MB
    unsigned* qv  = (unsigned*)w;         w += (size_t)NN * D * 4;   // 12.8 MB
    unsigned short* WnT = (unsigned short*)w;  w += 4 * D * D * 2;   // 32 KB
    unsigned short* WgT = (unsigned short*)w;  w += D * ED * 2;      // 4 KB
    unsigned short* WvT = (unsigned short*)w;  w += D * ED * 2;      // 4 KB
    int* deg  = (int*)w;                  w += (size_t)NN * 4;       // 200 KB
    int* gctr = (int*)w;                  w += 16;                   // 16 B
    int* off  = (int*)w;                  w += (size_t)NN * 4;       // 200 KB
    unsigned long long* rec = (unsigned long long*)w;                // 6.4 MB

    const int* srcI = eidx;
    const int* dstI = eidx + EE;

    // 1) weight prep + deg/gctr zero
    prep_zero<<<NB_PREP + NB_ZERO, 256, 0, stream>>>(Wk, Wq, Wv, Ws,
                                                     WnT, WgT, WvT, deg, gctr);
    // 2) node transforms + histogram
    node_hist<<<NB_NODE + NB_HIST, 256, 0, stream>>>(x, WnT, bk, bq, bv, bias,
                                                     kx, qv, out, dstI, deg);
    // 3) scan with atomic global base
    k_scanA<<<NB_SCAN, 256, 0, stream>>>(deg, off, gctr);
    // 4) scatter into dst-grouped records
    k_scatter4<<<NB_HIST, 256, 0, stream>>>(srcI, dstI, off, rec);
    // 5) aggregation
    agg_sorted<<<NT64 / 4, 256, 0, stream>>>((const unsigned*)rec, eatt,
                                             WgT, WvT, kx, qv, out);
}

// Round 13
// 175.262 us; speedup vs baseline: 1.2052x; 1.2052x over previous
//
#include <hip/hip_runtime.h>
#include <hip/hip_bf16.h>

#define D 64
#define ED 32
#define NN 50000
#define EE 800000
#define NT64 (EE / 64)   // 12500 64-edge tiles, exact
#define NWN (NN / 16)    // 3125 16-node tiles, exact

#define PREP_N (4 * D * D + D * ED)          // 18432 prep elements
#define NB_PREP ((PREP_N + 255) / 256)       // 72
#define NB_ZERO ((NN / 4 + 255) / 256)       // 49  (NN % 4 == 0)
#define NB_NODE ((NWN + 3) / 4)              // 782
#define NB_HIST ((EE / 4 + 255) / 256)       // 782 (EE % 4 == 0)
#define NB_SCAN ((NN + 255) / 256)           // 196

typedef __attribute__((ext_vector_type(8))) short bf16x8;
typedef __attribute__((ext_vector_type(4))) float f32x4;
typedef __attribute__((ext_vector_type(4))) unsigned uint4v;
typedef __attribute__((ext_vector_type(4))) int int4v;

__device__ __forceinline__ short f2bf(float f) {
    __hip_bfloat16 h = __float2bfloat16(f);
    return *reinterpret_cast<short*>(&h);
}
__device__ __forceinline__ float bfhi2f(unsigned w) { return __uint_as_float(w & 0xFFFF0000u); }
__device__ __forceinline__ float bflo2f(unsigned w) { return __uint_as_float(w << 16); }
__device__ __forceinline__ unsigned packqv(float q, float v) {
    return (unsigned)(unsigned short)f2bf(q) | ((unsigned)(unsigned short)f2bf(v) << 16);
}

// Fused: weight prep + deg/gctr zeroing. Edge tables COLUMN-PERMUTED:
// table row j holds original W column 4*(j&15)+(j>>4), so agg's C-fragment
// (lane lr, reg h) maps to logical dim 4*lr+h -> 16B vector gathers.
__global__ void prep_zero(const float* __restrict__ Wk, const float* __restrict__ Wq,
                          const float* __restrict__ Wv, const float* __restrict__ Ws,
                          unsigned short* __restrict__ WnT,
                          unsigned short* __restrict__ WgT, unsigned short* __restrict__ WvT,
                          int* __restrict__ deg, int* __restrict__ gctr) {
    const int b = blockIdx.x;
    if (b == 0 && threadIdx.x == 0) *gctr = 0;
    if (b < NB_PREP) {
        const int i = b * 256 + threadIdx.x;
        if (i < 4 * D * D) {
            // node tables stay in natural layout (node_hist epilogue uses 16h+lr)
            const int m = i >> 12, col = (i >> 6) & 63, k = i & 63;
            const float* W = (m == 0) ? Ws : (m == 1) ? Wk : (m == 2) ? Wq : Wv;
            WnT[i] = (unsigned short)f2bf(W[k * D + col]);
        } else {
            const int j = i - 4 * D * D;
            if (j < D * ED) {
                const int c = j >> 5, k = j & 31;
                const int cp = 4 * (c & 15) + (c >> 4);     // permuted column
                const size_t off = (size_t)(D + k) * D + cp;
                WgT[j] = (unsigned short)f2bf(Wk[off] + Wq[off]);
                WvT[j] = (unsigned short)f2bf(Wv[off]);
            }
        }
    } else {
        const int i = (b - NB_PREP) * 256 + threadIdx.x;   // int4 index
        if (i < NN / 4) ((int4v*)deg)[i] = (int4v){0, 0, 0, 0};
    }
}

// Mega-kernel: node MFMA transforms (pre-packed WnT) + dst histogram.
__global__ __launch_bounds__(256, 4)
void node_hist(const float* __restrict__ x, const unsigned short* __restrict__ WnT,
               const float* __restrict__ bk, const float* __restrict__ bq,
               const float* __restrict__ bv, const float* __restrict__ bias,
               float* __restrict__ kx, unsigned* __restrict__ qv, float* __restrict__ out,
               const int* __restrict__ dstI, int* __restrict__ deg) {
    const int b = blockIdx.x;
    if (b >= NB_NODE) {
        const int t = (b - NB_NODE) * 256 + threadIdx.x;
        const int e = 4 * t;
        if (e + 4 <= EE) {
            const int4v d4 = __builtin_nontemporal_load((const int4v*)(dstI + e));
#pragma unroll
            for (int r = 0; r < 4; ++r) atomicAdd(&deg[d4[r]], 1);
        }
        return;
    }
    const int lane = threadIdx.x & 63;
    const int wid  = b * 4 + (threadIdx.x >> 6);
    if (wid >= NWN) return;
    const int lg = lane >> 4, lr = lane & 15;
    const int n0 = wid * 16;

    const float* xp = x + (size_t)(n0 + lr) * D + 8 * lg;
    const f32x4 x00 = *(const f32x4*)xp;
    const f32x4 x01 = *(const f32x4*)(xp + 4);
    const f32x4 x10 = *(const f32x4*)(xp + 32);
    const f32x4 x11 = *(const f32x4*)(xp + 36);
    bf16x8 af0, af1;
#pragma unroll
    for (int e = 0; e < 4; ++e) {
        af0[e] = f2bf(x00[e]); af0[e + 4] = f2bf(x01[e]);
        af1[e] = f2bf(x10[e]); af1[e + 4] = f2bf(x11[e]);
    }

    f32x4 acc[4], accQ[4];
#pragma unroll
    for (int m = 0; m < 4; ++m) {
        f32x4* A = (m == 2) ? accQ : acc;
#pragma unroll
        for (int h = 0; h < 4; ++h) {
            const bf16x8 b0 = *(const bf16x8*)(WnT + (size_t)(m * D + 16 * h + lr) * D + 8 * lg);
            const bf16x8 b1 = *(const bf16x8*)(WnT + (size_t)(m * D + 16 * h + lr) * D + 32 + 8 * lg);
            A[h] = __builtin_amdgcn_mfma_f32_16x16x32_bf16(af0, b0, (f32x4)(0.f), 0, 0, 0);
            A[h] = __builtin_amdgcn_mfma_f32_16x16x32_bf16(af1, b1, A[h], 0, 0, 0);
        }
        if (m == 0) {
#pragma unroll
            for (int r = 0; r < 4; ++r)
#pragma unroll
                for (int h = 0; h < 4; ++h)
                    out[(size_t)(n0 + 4 * lg + r) * D + 16 * h + lr] = acc[h][r] + bias[16 * h + lr];
        } else if (m == 1) {
#pragma unroll
            for (int r = 0; r < 4; ++r)
#pragma unroll
                for (int h = 0; h < 4; ++h)
                    kx[(size_t)(n0 + 4 * lg + r) * D + 16 * h + lr] = acc[h][r] + bk[16 * h + lr];
        } else if (m == 3) {
#pragma unroll
            for (int r = 0; r < 4; ++r)
#pragma unroll
                for (int h = 0; h < 4; ++h)
                    qv[(size_t)(n0 + 4 * lg + r) * D + 16 * h + lr] =
                        packqv(accQ[h][r] + bq[16 * h + lr], acc[h][r] + bv[16 * h + lr]);
        }
    }
}

// Exclusive scan with atomic global base (proven).
__global__ void k_scanA(const int* __restrict__ deg, int* __restrict__ off,
                        int* __restrict__ gctr) {
    __shared__ int s_tmp[256];
    __shared__ int s_base;
    const int t = threadIdx.x, i = blockIdx.x * 256 + t;
    const int v = (i < NN) ? deg[i] : 0;
    s_tmp[t] = v;
    __syncthreads();
    for (int d = 1; d < 256; d <<= 1) {
        const int add = (t >= d) ? s_tmp[t - d] : 0;
        __syncthreads();
        s_tmp[t] += add;
        __syncthreads();
    }
    if (t == 255) s_base = atomicAdd(gctr, s_tmp[255]);
    __syncthreads();
    if (i < NN) off[i] = s_base + s_tmp[t] - v;
}

// Scatter, 4 edges/thread (proven).
__global__ void k_scatter4(const int* __restrict__ srcI, const int* __restrict__ dstI,
                           int* __restrict__ off, unsigned long long* __restrict__ rec) {
    const int t = blockIdx.x * 256 + threadIdx.x;
    const int e = 4 * t;
    if (e + 4 > EE) return;
    const int4v s4 = __builtin_nontemporal_load((const int4v*)(srcI + e));
    const int4v d4 = __builtin_nontemporal_load((const int4v*)(dstI + e));
#pragma unroll
    for (int r = 0; r < 4; ++r) {
        const int s = s4[r], d = d4[r];
        const int p = atomicAdd(&off[d], 1);
        rec[p] = ((unsigned long long)(unsigned)(e + r) << 32)
               | (unsigned)(s | (d << 16));
    }
}

// Edge-parallel aggregation over dst-grouped edges.
// Permuted-column C layout -> 16B vector gathers (r12 win, kept).
// Atomic scatter: shuffle-TRANSPOSE sh back to lane=dim order, then ONE
// contiguous 256B wave-atomic per run (fixes r12's 4x write amplification).
__global__ __launch_bounds__(256, 3)
void agg_sorted(const unsigned* __restrict__ rec, const float* __restrict__ ea,
                const unsigned short* __restrict__ WgT, const unsigned short* __restrict__ WvT,
                const float* __restrict__ kx, const unsigned* __restrict__ qv,
                float* __restrict__ out) {
    const int lane = threadIdx.x & 63;
    const int wid  = blockIdx.x * 4 + (threadIdx.x >> 6);   // tile id, grid exact
    const int lg = lane >> 4;
    const int lr = lane & 15;
    const int e0 = wid * 64;

    bf16x8 bg[4], bvf[4];
#pragma unroll
    for (int h = 0; h < 4; ++h) {
        bg[h]  = *(const bf16x8*)(WgT + (size_t)(16 * h + lr) * ED + 8 * lg);
        bvf[h] = *(const bf16x8*)(WvT + (size_t)(16 * h + lr) * ED + 8 * lg);
    }

#pragma unroll
    for (int g = 0; g < 4; ++g) {
        const int gb = e0 + 16 * g;
        const uint4v rA = *(const uint4v*)(rec + 2 * (gb + 4 * lg));
        const uint4v rB = *(const uint4v*)(rec + 2 * (gb + 4 * lg) + 4);
        int dR[4], sR[4];
        dR[0] = (int)(rA.x >> 16); sR[0] = (int)(rA.x & 0xFFFFu);
        dR[1] = (int)(rA.z >> 16); sR[1] = (int)(rA.z & 0xFFFFu);
        dR[2] = (int)(rB.x >> 16); sR[2] = (int)(rB.x & 0xFFFFu);
        dR[3] = (int)(rB.z >> 16); sR[3] = (int)(rB.z & 0xFFFFu);

        const unsigned pl = rec[2 * (gb + lr) + 1];
        const float* ap = ea + (size_t)pl * ED + 8 * lg;
        const f32x4 a0 = __builtin_nontemporal_load((const f32x4*)ap);
        const f32x4 a1 = __builtin_nontemporal_load((const f32x4*)(ap + 4));

        // vector gathers: per C-row one uint4 (qv) + one f32x4 (kx), dims 4lr..+3
        uint4v qd[4];
        f32x4  kd[4];
#pragma unroll
        for (int r = 0; r < 4; ++r) {
            qd[r] = *(const uint4v*)(qv + (size_t)sR[r] * D + 4 * lr);
            kd[r] = *(const f32x4*)(kx + (size_t)dR[r] * D + 4 * lr);
        }

        bf16x8 af;
#pragma unroll
        for (int e2 = 0; e2 < 4; ++e2) { af[e2] = f2bf(a0[e2]); af[e2 + 4] = f2bf(a1[e2]); }

        f32x4 accG[4], accV[4];
#pragma unroll
        for (int h = 0; h < 4; ++h) {
            accG[h] = __builtin_amdgcn_mfma_f32_16x16x32_bf16(af, bg[h],  (f32x4)(0.f), 0, 0, 0);
            accV[h] = __builtin_amdgcn_mfma_f32_16x16x32_bf16(af, bvf[h], (f32x4)(0.f), 0, 0, 0);
        }

        // msg[r][h]: edge gb+4lg+r, logical dim 4lr+h
        float msg[4][4];
#pragma unroll
        for (int r = 0; r < 4; ++r)
#pragma unroll
            for (int h = 0; h < 4; ++h) {
                const float z = accG[h][r] + kd[r][h] + bflo2f(qd[r][h]);
                const float v = accV[h][r] + bfhi2f(qd[r][h]);
                msg[r][h] = v * __builtin_amdgcn_rcpf(1.0f + __expf(-z));
            }

        bool done[4] = {false, false, false, false};
        while (true) {
            int m0 = 0x7FFFFFFF;
#pragma unroll
            for (int r = 0; r < 4; ++r) m0 = min(m0, done[r] ? 0x7FFFFFFF : dR[r]);
            m0 = min(m0, __shfl_xor(m0, 16, 64));
            m0 = min(m0, __shfl_xor(m0, 32, 64));
            if (m0 == 0x7FFFFFFF) break;          // wave-uniform exit
            float sh[4];
#pragma unroll
            for (int h = 0; h < 4; ++h) {
                float a = 0.f;
#pragma unroll
                for (int r = 0; r < 4; ++r) a += (dR[r] == m0) ? msg[r][h] : 0.f;
                a += __shfl_xor(a, 16, 64);
                a += __shfl_xor(a, 32, 64);
                sh[h] = a;        // every lane: run-total for dim 4*(lane&15)+h
            }
#pragma unroll
            for (int r = 0; r < 4; ++r) done[r] = done[r] || (dR[r] == m0);
            // transpose: lane j takes dim j = 4*(j>>2) + (j&3)
            const int qsrc = lane >> 2;
            const float t0 = __shfl(sh[0], qsrc, 64);
            const float t1 = __shfl(sh[1], qsrc, 64);
            const float t2 = __shfl(sh[2], qsrc, 64);
            const float t3 = __shfl(sh[3], qsrc, 64);
            const int hs = lane & 3;
            const float val = (hs == 0) ? t0 : (hs == 1) ? t1 : (hs == 2) ? t2 : t3;
            // one contiguous 256B wave-atomic per run
            unsafeAtomicAdd(&out[(size_t)m0 * D + lane], val);
        }
    }
}

extern "C" void kernel_launch(void* const* d_in, const int* in_sizes, int n_in,
                              void* d_out, int out_size, void* d_ws, size_t ws_size,
                              hipStream_t stream) {
    const float* x    = (const float*)d_in[0];
    const int*   eidx = (const int*)d_in[1];      // [2, E]: row0=src, row1=dst
    const float* eatt = (const float*)d_in[2];
    const float* Wk   = (const float*)d_in[3];
    const float* bk   = (const float*)d_in[4];
    const float* Wq   = (const float*)d_in[5];
    const float* bq   = (const float*)d_in[6];
    const float* Wv   = (const float*)d_in[7];
    const float* bv   = (const float*)d_in[8];
    const float* Ws   = (const float*)d_in[9];
    const float* bias = (const float*)d_in[10];
    float* out = (float*)d_out;

    // workspace carve (offsets keep 16B alignment)
    char* w = (char*)d_ws;
    float*    kx  = (float*)w;            w += (size_t)NN * D * 4;   // 12.8 MB
    unsigned* qv  = (unsigned*)w;         w += (size_t)NN * D * 4;   // 12.8 MB
    unsigned short* WnT = (unsigned short*)w;  w += 4 * D * D * 2;   // 32 KB
    unsigned short* WgT = (unsigned short*)w;  w += D * ED * 2;      // 4 KB
    unsigned short* WvT = (unsigned short*)w;  w += D * ED * 2;      // 4 KB
    int* deg  = (int*)w;                  w += (size_t)NN * 4;       // 200 KB
    int* gctr = (int*)w;                  w += 16;                   // 16 B
    int* off  = (int*)w;                  w += (size_t)NN * 4;       // 200 KB
    unsigned long long* rec = (unsigned long long*)w;                // 6.4 MB

    const int* srcI = eidx;
    const int* dstI = eidx + EE;

    // 1) weight prep + deg/gctr zero
    prep_zero<<<NB_PREP + NB_ZERO, 256, 0, stream>>>(Wk, Wq, Wv, Ws,
                                                     WnT, WgT, WvT, deg, gctr);
    // 2) node transforms + histogram
    node_hist<<<NB_NODE + NB_HIST, 256, 0, stream>>>(x, WnT, bk, bq, bv, bias,
                                                     kx, qv, out, dstI, deg);
    // 3) scan with atomic global base
    k_scanA<<<NB_SCAN, 256, 0, stream>>>(deg, off, gctr);
    // 4) scatter into dst-grouped records
    k_scatter4<<<NB_HIST, 256, 0, stream>>>(srcI, dstI, off, rec);
    // 5) aggregation
    agg_sorted<<<NT64 / 4, 256, 0, stream>>>((const unsigned*)rec, eatt,
                                             WgT, WvT, kx, qv, out);
}